// Round 2
// baseline (1002.597 us; speedup 1.0000x reference)
//
#include <hip/hip_runtime.h>
#include <hip/hip_bf16.h>

typedef unsigned short u16;

#define M_DIM 16384
#define N_DIM 4096
#define K_DIM 4096
#define R_DIM 64
#define BK 64
#define NT_K (K_DIM / BK)   // 64 K-tiles

typedef __bf16 bf16x8 __attribute__((ext_vector_type(8)));
typedef float floatx4 __attribute__((ext_vector_type(4)));
typedef u16 u16x8 __attribute__((ext_vector_type(8)));

__device__ __forceinline__ u16 f2bf(float f) {
    union { float f; unsigned int i; } v;
    v.f = f;
    unsigned int r = v.i + 0x7fffu + ((v.i >> 16) & 1u);  // RNE
    return (u16)(r >> 16);
}

// ---------------------------------------------------------------------------
// Kernel 0: fp32 -> bf16 round-convert (x). Each thread: 8 floats -> 8 bf16.
// ---------------------------------------------------------------------------
__global__ __launch_bounds__(256) void cvt_bf16(const float* __restrict__ in,
                                                u16* __restrict__ out, int n8) {
    int i = blockIdx.x * 256 + threadIdx.x;
    if (i >= n8) return;
    const float4* p = (const float4*)in + (size_t)i * 2;
    float4 a = p[0], b = p[1];
    u16x8 r;
    r[0] = f2bf(a.x); r[1] = f2bf(a.y); r[2] = f2bf(a.z); r[3] = f2bf(a.w);
    r[4] = f2bf(b.x); r[5] = f2bf(b.y); r[6] = f2bf(b.z); r[7] = f2bf(b.w);
    __builtin_nontemporal_store(r, (u16x8*)out + i);
}

// ---------------------------------------------------------------------------
// Kernel 1: fold LoRA into the weight (fp32 in, bf16 out).
// ---------------------------------------------------------------------------
__global__ __launch_bounds__(256) void prep_w(const float* __restrict__ W,
                                              const float* __restrict__ lA,
                                              const float* __restrict__ lB,
                                              u16* __restrict__ Wc) {
    __shared__ float Bs[16][R_DIM];
    const int k = blockIdx.x * 256 + threadIdx.x;
    const int n0 = blockIdx.y * 16;

    for (int i = threadIdx.x; i < 16 * R_DIM; i += 256) {
        int j = i >> 6, r = i & 63;
        Bs[j][r] = lB[(size_t)(n0 + j) * R_DIM + r];
    }
    __syncthreads();

    float acc[16];
#pragma unroll
    for (int j = 0; j < 16; ++j) acc[j] = 0.f;

    for (int r = 0; r < R_DIM; ++r) {
        float a = lA[(size_t)r * K_DIM + k];
#pragma unroll
        for (int j = 0; j < 16; ++j) acc[j] += Bs[j][r] * a;
    }

#pragma unroll
    for (int j = 0; j < 16; ++j) {
        size_t idx = (size_t)(n0 + j) * K_DIM + k;
        Wc[idx] = f2bf(W[idx] + acc[j]);
    }
}

// ---------------------------------------------------------------------------
// Kernel 2: 256x256-tile 8-phase GEMM (T1+T2+T3+T4+T5 port).
// C[M][N] = A[M][K](bf16) @ B[N][K](bf16)^T + bias, C f32.
//
// 8 waves (2M x 4N), BK=64, LDS = 2 buf x {A,B} x 2 halves x [128][64] bf16
// = 128 KiB. Phase p computes block-quadrant (qm,qn) in order
// (0,0),(1,0),(1,1),(0,1); each wave owns a 64x32 piece of every quadrant,
// so half-tile needs are wave-uniform: Ah0,Bh0 @P0; Ah1 @P1; Bh1 @P2.
// Stage order [Ah0,Bh0,Ah1,Bh1], one half per phase, one tile ahead, issued
// AFTER the phase barrier. Ledger (2 loads/half):
//   P0: queue = incoming tile's 8 loads -> vmcnt(4) drains {Ah0,Bh0}
//   P1: queue = [Ah1,Bh1,S0] = 6       -> vmcnt(4) drains Ah1
//   P2: queue = [Bh1,S0,S1] = 6        -> vmcnt(4) drains Bh1
//   P3: nothing new needed             -> no wait
// Never vmcnt(0) in the main loop (T4). One s_barrier per phase; stages for
// buf X are issued only after the barrier that all readers of X's previous
// tile have passed (P4-read -> P5-barrier -> P5-stage etc).
// LDS swizzle (T2, st_16x32): linear LDS dest, source global address
// pre-swizzled col ^= ((row>>2)&1)<<4 elems; reads apply the same XOR.
// ---------------------------------------------------------------------------

#define STAGE_HALF(SB, AB, H, TS) do {                                        \
    const u16* _g = (AB ? gB : gA) +                                          \
        ((size_t)((H) * 128) * K_DIM + (size_t)(TS) * BK);                    \
    __builtin_amdgcn_global_load_lds(                                         \
        (const __attribute__((address_space(1))) void*)_g,                    \
        (__attribute__((address_space(3))) void*)&lds[SB][AB][H][tid * 8],    \
        16, 0, 0);                                                            \
    __builtin_amdgcn_global_load_lds(                                         \
        (const __attribute__((address_space(1))) void*)(_g + (size_t)64 * K_DIM), \
        (__attribute__((address_space(3))) void*)&lds[SB][AB][H][4096 + tid * 8], \
        16, 0, 0);                                                            \
  } while (0)

#define LOAD_AF(BUF, QM) do {                                                 \
    const u16* _ba = &lds[BUF][0][QM][0];                                     \
    _Pragma("unroll") for (int mt = 0; mt < 4; ++mt) {                        \
      af[mt][0] = *(const bf16x8*)(_ba + arow[mt] + koff0);                   \
      af[mt][1] = *(const bf16x8*)(_ba + arow[mt] + koff1);                   \
    }                                                                         \
  } while (0)

#define LOAD_BF(BUF, QN) do {                                                 \
    const u16* _bb = &lds[BUF][1][QN][0];                                     \
    _Pragma("unroll") for (int nt = 0; nt < 2; ++nt) {                        \
      bfr[nt][0] = *(const bf16x8*)(_bb + brow[nt] + koff0);                  \
      bfr[nt][1] = *(const bf16x8*)(_bb + brow[nt] + koff1);                  \
    }                                                                         \
  } while (0)

#define MFMA16(M0, N0) do {                                                   \
    __builtin_amdgcn_s_setprio(1);                                            \
    _Pragma("unroll") for (int mt = 0; mt < 4; ++mt)                          \
      _Pragma("unroll") for (int nt = 0; nt < 2; ++nt)                        \
        _Pragma("unroll") for (int ks = 0; ks < 2; ++ks)                      \
          acc[M0 + mt][N0 + nt] = __builtin_amdgcn_mfma_f32_16x16x32_bf16(    \
              af[mt][ks], bfr[nt][ks], acc[M0 + mt][N0 + nt], 0, 0, 0);       \
    __builtin_amdgcn_s_setprio(0);                                            \
  } while (0)

#define PH(WAIT, SB, SAB, SH, TS, DOA, QM, DOB, QN, M0, N0, BUF)              \
  do {                                                                        \
    if (WAIT) asm volatile("s_waitcnt vmcnt(4)" ::: "memory");                \
    __builtin_amdgcn_s_barrier();                                             \
    __builtin_amdgcn_sched_barrier(0);                                        \
    STAGE_HALF(SB, SAB, SH, TS);                                              \
    if (DOA) LOAD_AF(BUF, QM);                                                \
    if (DOB) LOAD_BF(BUF, QN);                                                \
    MFMA16(M0, N0);                                                           \
  } while (0)

__global__ __launch_bounds__(512, 2) void gemm_bias(
    const u16* __restrict__ A,      // x bf16 [M][K]
    const u16* __restrict__ B,      // W_comb bf16 [N][K]
    const float* __restrict__ bias, // [N] f32
    float* __restrict__ C) {        // [M][N] f32
    __shared__ __align__(16) u16 lds[2][2][2][8192]; // [buf][A/B][half][128*64]

    const int tid  = threadIdx.x;
    const int lane = tid & 63;
    const int wave = tid >> 6;   // 0..7
    const int wm = wave >> 2;    // 0..1
    const int wn = wave & 3;     // 0..3

    // XCD-bijective swizzle (nwg=1024, %8==0): XCD x gets id2 in
    // [x*128, x*128+127] = 2 full bn columns x 64 bm -> its 2 B-panels
    // (4 MB) stay L2-hot; A re-reads hit L3 (A=128MB < 256MB).
    const int bid = blockIdx.x;
    const int id2 = (bid & 7) * 128 + (bid >> 3);
    const int bm = id2 & 63;     // 64 M-tiles
    const int bn = id2 >> 6;     // 16 N-tiles
    const int m0 = bm * 256;
    const int n0 = bn * 256;

    // staging: thread t -> rows (t>>3) and 64+(t>>3) of a half, 16B each;
    // source col pre-swizzled so linear LDS dest holds swizzled layout.
    const int srow = tid >> 3;                                    // 0..63
    const int scol = ((tid & 7) * 8) ^ (((tid >> 5) & 1) << 4);   // elems
    const u16* gA = A + (size_t)(m0 + srow) * K_DIM + scol;
    const u16* gB = B + (size_t)(n0 + srow) * K_DIM + scol;

    // fragment read offsets (elems within a [128][64] half, swizzled):
    // row bit2 == frow bit2 == (lane>>2)&1
    const int frow = lane & 15;
    const int swe  = ((lane >> 2) & 1) << 4;
    const int k0e  = (lane >> 4) * 8;
    const int koff0 = (k0e) ^ swe;
    const int koff1 = (32 + k0e) ^ swe;
    int arow[4], brow[2];
#pragma unroll
    for (int mt = 0; mt < 4; ++mt) arow[mt] = (wm * 64 + mt * 16 + frow) * 64;
#pragma unroll
    for (int nt = 0; nt < 2; ++nt) brow[nt] = (wn * 32 + nt * 16 + frow) * 64;

    floatx4 acc[8][4];
#pragma unroll
    for (int i = 0; i < 8; ++i)
#pragma unroll
        for (int j = 0; j < 4; ++j) acc[i][j] = (floatx4){0.f, 0.f, 0.f, 0.f};

    bf16x8 af[4][2], bfr[2][2];

    // prologue: stage tile 0 into buf0, order [Ah0, Bh0, Ah1, Bh1]
    STAGE_HALF(0, 0, 0, 0);
    STAGE_HALF(0, 1, 0, 0);
    STAGE_HALF(0, 0, 1, 0);
    STAGE_HALF(0, 1, 1, 0);

    for (int t = 0; t < NT_K; t += 2) {
        const int tsa = t + 1;                 // staged during even tile
        const int tsb = (t + 2) & (NT_K - 1);  // staged during odd tile (wraps)
        // tile t (buf0), stage tile t+1 -> buf1
        PH(1, 1, 0, 0, tsa, 1, 0, 1, 0, 0, 0, 0); // Q(0,0): ld A0,B0
        PH(1, 1, 1, 0, tsa, 1, 1, 0, 0, 4, 0, 0); // Q(1,0): ld A1, keep B0
        PH(1, 1, 0, 1, tsa, 0, 0, 1, 1, 4, 2, 0); // Q(1,1): keep A1, ld B1
        PH(0, 1, 1, 1, tsa, 1, 0, 0, 0, 0, 2, 0); // Q(0,1): ld A0, keep B1
        // tile t+1 (buf1), stage tile t+2 -> buf0
        PH(1, 0, 0, 0, tsb, 1, 0, 1, 0, 0, 0, 1);
        PH(1, 0, 1, 0, tsb, 1, 1, 0, 0, 4, 0, 1);
        PH(1, 0, 0, 1, tsb, 0, 0, 1, 1, 4, 2, 1);
        PH(0, 0, 1, 1, tsb, 1, 0, 0, 0, 0, 2, 1);
    }
    asm volatile("s_waitcnt vmcnt(0)" ::: "memory"); // drain trailing stages

    // epilogue: C/D layout col = lane&15, row = (lane>>4)*4 + r
    // nontemporal: C (256MB) is write-once; don't evict L2-resident B panels.
#pragma unroll
    for (int qm = 0; qm < 2; ++qm)
#pragma unroll
    for (int qn = 0; qn < 2; ++qn)
#pragma unroll
    for (int mt = 0; mt < 4; ++mt)
#pragma unroll
    for (int nt = 0; nt < 2; ++nt) {
        const int col = n0 + qn * 128 + wn * 32 + nt * 16 + (lane & 15);
        const float bv = bias[col];
        const int row0 = m0 + qm * 128 + wm * 64 + mt * 16 + ((lane >> 4) << 2);
        floatx4 v = acc[qm * 4 + mt][qn * 2 + nt];
#pragma unroll
        for (int r = 0; r < 4; ++r)
            __builtin_nontemporal_store(v[r] + bv,
                &C[(size_t)(row0 + r) * N_DIM + col]);
    }
}

extern "C" void kernel_launch(void* const* d_in, const int* in_sizes, int n_in,
                              void* d_out, int out_size, void* d_ws, size_t ws_size,
                              hipStream_t stream) {
    const float* x    = (const float*)d_in[0];  // [M][K] f32
    const float* W    = (const float*)d_in[1];  // [N][K] f32
    const float* bias = (const float*)d_in[2];  // [N] f32
    const float* lA   = (const float*)d_in[3];  // [R][K] f32
    const float* lB   = (const float*)d_in[4];  // [N][R] f32
    float* out = (float*)d_out;                 // [M][N] f32

    // workspace: Wc bf16 [N*K] (32 MB), then x_bf16 [M*K] (128 MB)
    u16* Wc = (u16*)d_ws;
    u16* xb = Wc + (size_t)N_DIM * K_DIM;

    cvt_bf16<<<dim3((M_DIM * K_DIM / 8 + 255) / 256), 256, 0, stream>>>(
        x, xb, M_DIM * K_DIM / 8);

    dim3 g1(K_DIM / 256, N_DIM / 16);
    prep_w<<<g1, 256, 0, stream>>>(W, lA, lB, Wc);

    // 64 x 16 = 1024 blocks, 512 threads, 1 block/CU
    gemm_bias<<<dim3(1024), 512, 0, stream>>>(xb, Wc, bias, out);
}

// Round 3
// 940.257 us; speedup vs baseline: 1.0663x; 1.0663x over previous
//
#include <hip/hip_runtime.h>
#include <hip/hip_bf16.h>

typedef unsigned short u16;

#define M_DIM 16384
#define N_DIM 4096
#define K_DIM 4096
#define R_DIM 64
#define BK 64
#define NT_K (K_DIM / BK)   // 64 K-tiles

typedef __bf16 bf16x8 __attribute__((ext_vector_type(8)));
typedef float floatx4 __attribute__((ext_vector_type(4)));
typedef u16 u16x8 __attribute__((ext_vector_type(8)));

__device__ __forceinline__ u16 f2bf(float f) {
    union { float f; unsigned int i; } v;
    v.f = f;
    unsigned int r = v.i + 0x7fffu + ((v.i >> 16) & 1u);  // RNE
    return (u16)(r >> 16);
}

// ---------------------------------------------------------------------------
// Kernel 0: fp32 -> bf16 round-convert (x). Each thread: 8 floats -> 8 bf16.
// ---------------------------------------------------------------------------
__global__ __launch_bounds__(256) void cvt_bf16(const float* __restrict__ in,
                                                u16* __restrict__ out, int n8) {
    int i = blockIdx.x * 256 + threadIdx.x;
    if (i >= n8) return;
    const float4* p = (const float4*)in + (size_t)i * 2;
    float4 a = p[0], b = p[1];
    u16x8 r;
    r[0] = f2bf(a.x); r[1] = f2bf(a.y); r[2] = f2bf(a.z); r[3] = f2bf(a.w);
    r[4] = f2bf(b.x); r[5] = f2bf(b.y); r[6] = f2bf(b.z); r[7] = f2bf(b.w);
    __builtin_nontemporal_store(r, (u16x8*)out + i);
}

// ---------------------------------------------------------------------------
// Kernel 1: fold LoRA into the weight (fp32 in, bf16 out).
// ---------------------------------------------------------------------------
__global__ __launch_bounds__(256) void prep_w(const float* __restrict__ W,
                                              const float* __restrict__ lA,
                                              const float* __restrict__ lB,
                                              u16* __restrict__ Wc) {
    __shared__ float Bs[16][R_DIM];
    const int k = blockIdx.x * 256 + threadIdx.x;
    const int n0 = blockIdx.y * 16;

    for (int i = threadIdx.x; i < 16 * R_DIM; i += 256) {
        int j = i >> 6, r = i & 63;
        Bs[j][r] = lB[(size_t)(n0 + j) * R_DIM + r];
    }
    __syncthreads();

    float acc[16];
#pragma unroll
    for (int j = 0; j < 16; ++j) acc[j] = 0.f;

    for (int r = 0; r < R_DIM; ++r) {
        float a = lA[(size_t)r * K_DIM + k];
#pragma unroll
        for (int j = 0; j < 16; ++j) acc[j] += Bs[j][r] * a;
    }

#pragma unroll
    for (int j = 0; j < 16; ++j) {
        size_t idx = (size_t)(n0 + j) * K_DIM + k;
        Wc[idx] = f2bf(W[idx] + acc[j]);
    }
}

// ---------------------------------------------------------------------------
// Kernel 2: 256x256-tile 8-phase GEMM (T1+T2+T3+T4+T5).
// C[M][N] = A[M][K](bf16) @ B[N][K](bf16)^T + bias, C f32.
//
// 8 waves (2M x 4N), BK=64, LDS = 2 buf x {A,B} x 2 halves x [128][64] bf16
// = 128 KiB. Phases compute quadrants (0,0),(1,0),(1,1),(0,1).
// A-fragments for qm=0 (afA) and qm=1 (afB) are kept in separate registers,
// so P3 reuses P0's afA with NO ds_read (saves 8 b128/tile/wave).
//
// vmcnt ledger (2 loads/half, stage issued AFTER the phase barrier):
//   P0: queue = incoming tile's 8 loads -> vmcnt(4) drains {Ah0,Bh0}
//   P1: queue = [Ah1,Bh1,S0] = 6       -> vmcnt(4) drains Ah1
//   P2: queue = [Bh1,S0,S1] = 6        -> vmcnt(4) drains Bh1
//   P3: nothing new needed             -> no wait
// Never vmcnt(0) in the main loop (T4).
//
// LDS swizzle (full 3-bit XOR, G4): row stride = 128B = 32 banks, so the
// bank-quad is purely the 16B slot (8/row). Involution slot' = slot ^ (row&7)
// applied to BOTH the staging source column and the read offset. Each 8-lane
// issue group of ds_read_b128 (consecutive rows, fixed slot) then covers all
// 8 slots bijectively -> conflict-free. (Round-2 single-bit version left a
// 4-way conflict: 6.7e7 SQ_LDS_BANK_CONFLICT.)
// ---------------------------------------------------------------------------

#define STAGE_HALF(SB, AB, H, TS) do {                                        \
    const u16* _g = (AB ? gB : gA) +                                          \
        ((size_t)((H) * 128) * K_DIM + (size_t)(TS) * BK);                    \
    __builtin_amdgcn_global_load_lds(                                         \
        (const __attribute__((address_space(1))) void*)_g,                    \
        (__attribute__((address_space(3))) void*)&lds[SB][AB][H][tid * 8],    \
        16, 0, 0);                                                            \
    __builtin_amdgcn_global_load_lds(                                         \
        (const __attribute__((address_space(1))) void*)(_g + (size_t)64 * K_DIM), \
        (__attribute__((address_space(3))) void*)&lds[SB][AB][H][4096 + tid * 8], \
        16, 0, 0);                                                            \
  } while (0)

#define LOAD_AF(DST, BUF, QM) do {                                           \
    const u16* _ba = &lds[BUF][0][QM][0];                                    \
    _Pragma("unroll") for (int mt = 0; mt < 4; ++mt) {                       \
      DST[mt][0] = *(const bf16x8*)(_ba + arow[mt] + koff0);                 \
      DST[mt][1] = *(const bf16x8*)(_ba + arow[mt] + koff1);                 \
    }                                                                        \
  } while (0)

#define LOAD_BF(BUF, QN) do {                                                \
    const u16* _bb = &lds[BUF][1][QN][0];                                    \
    _Pragma("unroll") for (int nt = 0; nt < 2; ++nt) {                       \
      bfr[nt][0] = *(const bf16x8*)(_bb + brow[nt] + koff0);                 \
      bfr[nt][1] = *(const bf16x8*)(_bb + brow[nt] + koff1);                 \
    }                                                                        \
  } while (0)

#define MFMA16(AF, M0, N0) do {                                              \
    __builtin_amdgcn_s_setprio(1);                                           \
    _Pragma("unroll") for (int mt = 0; mt < 4; ++mt)                         \
      _Pragma("unroll") for (int nt = 0; nt < 2; ++nt)                       \
        _Pragma("unroll") for (int ks = 0; ks < 2; ++ks)                     \
          acc[M0 + mt][N0 + nt] = __builtin_amdgcn_mfma_f32_16x16x32_bf16(   \
              AF[mt][ks], bfr[nt][ks], acc[M0 + mt][N0 + nt], 0, 0, 0);      \
    __builtin_amdgcn_s_setprio(0);                                           \
  } while (0)

// DOA: 0=no A-load, 1=load afA, 2=load afB.  AF: which A-regs feed the MFMA.
#define PH(WAIT, SB, SAB, SH, TS, DOA, QM, DOB, QN, AF, M0, N0, BUF)         \
  do {                                                                       \
    if (WAIT) asm volatile("s_waitcnt vmcnt(4)" ::: "memory");               \
    __builtin_amdgcn_s_barrier();                                            \
    __builtin_amdgcn_sched_barrier(0);                                       \
    STAGE_HALF(SB, SAB, SH, TS);                                             \
    if (DOA == 1) LOAD_AF(afA, BUF, QM);                                     \
    if (DOA == 2) LOAD_AF(afB, BUF, QM);                                     \
    if (DOB) LOAD_BF(BUF, QN);                                               \
    MFMA16(AF, M0, N0);                                                      \
  } while (0)

__global__ __launch_bounds__(512, 2) void gemm_bias(
    const u16* __restrict__ A,      // x bf16 [M][K]
    const u16* __restrict__ B,      // W_comb bf16 [N][K]
    const float* __restrict__ bias, // [N] f32
    float* __restrict__ C) {        // [M][N] f32
    __shared__ __align__(16) u16 lds[2][2][2][8192]; // [buf][A/B][half][128*64]

    const int tid  = threadIdx.x;
    const int lane = tid & 63;
    const int wave = tid >> 6;   // 0..7
    const int wm = wave >> 2;    // 0..1
    const int wn = wave & 3;     // 0..3

    // XCD-bijective swizzle (nwg=1024, %8==0): XCD x gets 2 full bn columns
    // x 64 bm -> its 2 B-panels (4 MB) stay L2-hot.
    const int bid = blockIdx.x;
    const int id2 = (bid & 7) * 128 + (bid >> 3);
    const int bm = id2 & 63;     // 64 M-tiles
    const int bn = id2 >> 6;     // 16 N-tiles
    const int m0 = bm * 256;
    const int n0 = bn * 256;

    // staging: thread t -> rows (t>>3) and 64+(t>>3) of a half, 16B each.
    // Source 16B-slot permuted by slot ^= (row&7): linear LDS dest then holds
    // the swizzled layout (both-sides involution).
    const int srow = tid >> 3;                                    // 0..63
    const int scol = (((tid & 7) ^ ((tid >> 3) & 7)) * 8);        // elems
    const u16* gA = A + (size_t)(m0 + srow) * K_DIM + scol;
    const u16* gB = B + (size_t)(n0 + srow) * K_DIM + scol;

    // fragment read offsets (elems within a [128][64] half, swizzled):
    // row&7 == lane&7 for every fragment row (bases are multiples of 16).
    const int frow = lane & 15;
    const int sw   = (lane & 7) << 3;           // (row&7)*8 elems
    const int k0e  = (lane >> 4) * 8;
    const int koff0 = (k0e) ^ sw;
    const int koff1 = (32 + k0e) ^ sw;
    int arow[4], brow[2];
#pragma unroll
    for (int mt = 0; mt < 4; ++mt) arow[mt] = (wm * 64 + mt * 16 + frow) * 64;
#pragma unroll
    for (int nt = 0; nt < 2; ++nt) brow[nt] = (wn * 32 + nt * 16 + frow) * 64;

    floatx4 acc[8][4];
#pragma unroll
    for (int i = 0; i < 8; ++i)
#pragma unroll
        for (int j = 0; j < 4; ++j) acc[i][j] = (floatx4){0.f, 0.f, 0.f, 0.f};

    bf16x8 afA[4][2], afB[4][2], bfr[2][2];

    // prologue: stage tile 0 into buf0, order [Ah0, Bh0, Ah1, Bh1]
    STAGE_HALF(0, 0, 0, 0);
    STAGE_HALF(0, 1, 0, 0);
    STAGE_HALF(0, 0, 1, 0);
    STAGE_HALF(0, 1, 1, 0);

    for (int t = 0; t < NT_K; t += 2) {
        const int tsa = t + 1;                 // staged during even tile
        const int tsb = (t + 2) & (NT_K - 1);  // staged during odd tile (wraps)
        // tile t (buf0), stage tile t+1 -> buf1
        PH(1, 1, 0, 0, tsa, 1, 0, 1, 0, afA, 0, 0, 0); // Q(0,0): ld afA,B0
        PH(1, 1, 1, 0, tsa, 2, 1, 0, 0, afB, 4, 0, 0); // Q(1,0): ld afB
        PH(1, 1, 0, 1, tsa, 0, 0, 1, 1, afB, 4, 2, 0); // Q(1,1): ld B1
        PH(0, 1, 1, 1, tsa, 0, 0, 0, 0, afA, 0, 2, 0); // Q(0,1): regs only
        // tile t+1 (buf1), stage tile t+2 -> buf0
        PH(1, 0, 0, 0, tsb, 1, 0, 1, 0, afA, 0, 0, 1);
        PH(1, 0, 1, 0, tsb, 2, 1, 0, 0, afB, 4, 0, 1);
        PH(1, 0, 0, 1, tsb, 0, 0, 1, 1, afB, 4, 2, 1);
        PH(0, 0, 1, 1, tsb, 0, 0, 0, 0, afA, 0, 2, 1);
    }
    asm volatile("s_waitcnt vmcnt(0)" ::: "memory"); // drain trailing stages

    // epilogue: C/D layout col = lane&15, row = (lane>>4)*4 + r
    // nontemporal: C is write-once; don't evict L2-resident B panels.
#pragma unroll
    for (int qm = 0; qm < 2; ++qm)
#pragma unroll
    for (int qn = 0; qn < 2; ++qn)
#pragma unroll
    for (int mt = 0; mt < 4; ++mt)
#pragma unroll
    for (int nt = 0; nt < 2; ++nt) {
        const int col = n0 + qn * 128 + wn * 32 + nt * 16 + (lane & 15);
        const float bv = bias[col];
        const int row0 = m0 + qm * 128 + wm * 64 + mt * 16 + ((lane >> 4) << 2);
        floatx4 v = acc[qm * 4 + mt][qn * 2 + nt];
#pragma unroll
        for (int r = 0; r < 4; ++r)
            __builtin_nontemporal_store(v[r] + bv,
                &C[(size_t)(row0 + r) * N_DIM + col]);
    }
}

extern "C" void kernel_launch(void* const* d_in, const int* in_sizes, int n_in,
                              void* d_out, int out_size, void* d_ws, size_t ws_size,
                              hipStream_t stream) {
    const float* x    = (const float*)d_in[0];  // [M][K] f32
    const float* W    = (const float*)d_in[1];  // [N][K] f32
    const float* bias = (const float*)d_in[2];  // [N] f32
    const float* lA   = (const float*)d_in[3];  // [R][K] f32
    const float* lB   = (const float*)d_in[4];  // [N][R] f32
    float* out = (float*)d_out;                 // [M][N] f32

    // workspace: Wc bf16 [N*K] (32 MB), then x_bf16 [M*K] (128 MB)
    u16* Wc = (u16*)d_ws;
    u16* xb = Wc + (size_t)N_DIM * K_DIM;

    cvt_bf16<<<dim3((M_DIM * K_DIM / 8 + 255) / 256), 256, 0, stream>>>(
        x, xb, M_DIM * K_DIM / 8);

    dim3 g1(K_DIM / 256, N_DIM / 16);
    prep_w<<<g1, 256, 0, stream>>>(W, lA, lB, Wc);

    // 64 x 16 = 1024 blocks, 512 threads, 1 block/CU
    gemm_bias<<<dim3(1024), 512, 0, stream>>>(xb, Wc, bias, out);
}